// Round 1
// baseline (2080.061 us; speedup 1.0000x reference)
//
#include <hip/hip_runtime.h>

#define BS 256

// ---- problem dims ----
constexpr int D1=41, H1=200, W1=176; constexpr int N1v=D1*H1*W1;   // 1,443,200
constexpr int D2=21, H2=100, W2=88;  constexpr int N2v=D2*H2*W2;   //   184,800
constexpr int D3=11, H3=50,  W3=44;  constexpr int N3v=D3*H3*W3;   //    24,200
constexpr int D4=5,  H4=25,  W4=22;  constexpr int N4v=D4*H4*W4;   //     2,750
constexpr int DOo=2, HOo=25, WOo=22;                                // out spatial
constexpr int ROWS1=65536;   // cap on level-1 active sites (actual ~29k at 2% density)

// ---- bf16 helpers ----
__device__ __forceinline__ float bflo(unsigned int u){ return __uint_as_float(u<<16); }
__device__ __forceinline__ float bfhi(unsigned int u){ return __uint_as_float(u & 0xffff0000u); }
__device__ __forceinline__ unsigned short f2bf(float f){
  unsigned int x = __float_as_uint(f);
  x += 0x7fffu + ((x>>16)&1u);             // round-to-nearest-even
  return (unsigned short)(x>>16);
}
// accumulate 8 bf16 inputs (one uint4) against weights strided by `stride`
__device__ __forceinline__ void acc8(float& acc, uint4 p, const float* __restrict__ wk, int stride){
  acc = fmaf(bflo(p.x), wk[0*stride], acc);
  acc = fmaf(bfhi(p.x), wk[1*stride], acc);
  acc = fmaf(bflo(p.y), wk[2*stride], acc);
  acc = fmaf(bfhi(p.y), wk[3*stride], acc);
  acc = fmaf(bflo(p.z), wk[4*stride], acc);
  acc = fmaf(bfhi(p.z), wk[5*stride], acc);
  acc = fmaf(bflo(p.w), wk[6*stride], acc);
  acc = fmaf(bfhi(p.w), wk[7*stride], acc);
}

// ---- fold BN into weights, transpose to [ktap][ci][cout] ----
__global__ void prep_weights(const float* __restrict__ w, const float* __restrict__ bn,
                             float* __restrict__ wt, float* __restrict__ bias,
                             int O, int I, int K){
  int t = blockIdx.x*BS + threadIdx.x;
  int total = O*I*K;
  if (t >= total) return;
  int k = t % K; int rest = t / K; int ci = rest % I; int o = rest / I;
  float g = bn[o], b = bn[O+o], m = bn[2*O+o], v = bn[3*O+o];
  float scale = g * rsqrtf(v + 1e-3f);
  wt[(k*I+ci)*O + o] = w[(o*I+ci)*K + k] * scale;
  if (ci==0 && k==0) bias[o] = b - m*scale;
}

// ---- level-1 active list + site->row index grid ----
__global__ void build_list1_kernel(const float* __restrict__ mask,
                                   int* __restrict__ I1, int* __restrict__ list1,
                                   int* __restrict__ cnt){
  int s = blockIdx.x*BS + threadIdx.x;
  if (s >= N1v) return;
  if (mask[s] > 0.f){
    int r = atomicAdd(cnt, 1);
    if (r < ROWS1){ list1[r] = s; I1[s] = r; }
  }
}

// ---- maxpool mask (k=3 s=2), build next-level mask + active list ----
template<int DI,int HI,int WI,int DOUT,int HOUT,int WOUT,int PZ,int PY,int PX>
__global__ void build_mask_kernel(const float* __restrict__ min_,
                                  float* __restrict__ mout,
                                  int* __restrict__ list, int* __restrict__ cnt1){
  int s = blockIdx.x*BS + threadIdx.x;
  if (s >= DOUT*HOUT*WOUT) return;
  int z = s/(HOUT*WOUT); int r = s - z*(HOUT*WOUT); int y = r/WOUT; int x = r - y*WOUT;
  bool act = false;
  for (int dz=0; dz<3 && !act; dz++){ int zz = 2*z - PZ + dz; if ((unsigned)zz >= (unsigned)DI) continue;
    for (int dy=0; dy<3 && !act; dy++){ int yy = 2*y - PY + dy; if ((unsigned)yy >= (unsigned)HI) continue;
      for (int dx=0; dx<3; dx++){ int xc = 2*x - PX + dx; if ((unsigned)xc >= (unsigned)WI) continue;
        if (min_[(zz*HI+yy)*WI+xc] > 0.f){ act = true; break; }
      }}}
  mout[s] = act ? 1.f : 0.f;
  if (act){ int r2 = atomicAdd(cnt1, 1); list[r2] = s; }
}

// ---- layer 0: subm conv 4->16 at level 1, dense f32 input x, compact bf16 output ----
__global__ void subm_l0_kernel(const float* __restrict__ x,
                               const int* __restrict__ list1, const int* __restrict__ cnt,
                               const float* __restrict__ wt, const float* __restrict__ bias,
                               unsigned short* __restrict__ fout){
  int t = blockIdx.x*BS + threadIdx.x;
  int row = t >> 4, cout = t & 15;
  if (row >= cnt[0]) return;
  int s = list1[row];
  int z = s/(H1*W1); int r = s - z*(H1*W1); int y = r/W1; int xx = r - y*W1;
  float acc = bias[cout];
  for (int dz=-1; dz<=1; dz++){ int zz=z+dz; if ((unsigned)zz >= (unsigned)D1) continue;
    for (int dy=-1; dy<=1; dy++){ int yy=y+dy; if ((unsigned)yy >= (unsigned)H1) continue;
      for (int dx=-1; dx<=1; dx++){ int xc=xx+dx; if ((unsigned)xc >= (unsigned)W1) continue;
        int ns = (zz*H1+yy)*W1+xc;
        int k = ((dz+1)*3+(dy+1))*3+(dx+1);
        const float* wk = wt + k*4*16 + cout;
        #pragma unroll
        for (int ci=0; ci<4; ci++) acc = fmaf(x[ci*N1v+ns], wk[ci*16], acc);
      }}}
  fout[row*16+cout] = f2bf(fmaxf(acc, 0.f));
}

// ---- layer 1: subm conv 16->16 at level 1, compact in/out via index grid ----
__global__ void subm_l1_kernel(const unsigned short* __restrict__ fin,
                               const int* __restrict__ I1,
                               const int* __restrict__ list1, const int* __restrict__ cnt,
                               const float* __restrict__ wt, const float* __restrict__ bias,
                               unsigned short* __restrict__ fout){
  int t = blockIdx.x*BS + threadIdx.x;
  int row = t >> 4, cout = t & 15;
  if (row >= cnt[0]) return;
  int s = list1[row];
  int z = s/(H1*W1); int r = s - z*(H1*W1); int y = r/W1; int xx = r - y*W1;
  float acc = bias[cout];
  for (int dz=-1; dz<=1; dz++){ int zz=z+dz; if ((unsigned)zz >= (unsigned)D1) continue;
    for (int dy=-1; dy<=1; dy++){ int yy=y+dy; if ((unsigned)yy >= (unsigned)H1) continue;
      for (int dx=-1; dx<=1; dx++){ int xc=xx+dx; if ((unsigned)xc >= (unsigned)W1) continue;
        int ns = (zz*H1+yy)*W1+xc;
        int rr = I1[ns]; if (rr < 0) continue;
        int k = ((dz+1)*3+(dy+1))*3+(dx+1);
        const float* wk = wt + k*16*16 + cout;
        const uint4* fr = (const uint4*)(fin + (size_t)rr*16);
        #pragma unroll
        for (int q=0; q<2; q++) acc8(acc, fr[q], wk + q*8*16, 16);
      }}}
  fout[row*16+cout] = f2bf(fmaxf(acc, 0.f));
}

// ---- layer 2: spconv 16->32 stride2 pad1, compact level-1 input -> dense level-2 out ----
__global__ void spconv_l2_kernel(const unsigned short* __restrict__ fin,
                                 const int* __restrict__ I1,
                                 const int* __restrict__ list2, const int* __restrict__ cnt,
                                 const float* __restrict__ wt, const float* __restrict__ bias,
                                 unsigned short* __restrict__ gout){
  int t = blockIdx.x*BS + threadIdx.x;
  int row = t >> 5, cout = t & 31;
  if (row >= cnt[1]) return;
  int s = list2[row];
  int z = s/(H2*W2); int r = s - z*(H2*W2); int y = r/W2; int xx = r - y*W2;
  float acc = bias[cout];
  for (int dz=0; dz<3; dz++){ int zz = 2*z-1+dz; if ((unsigned)zz >= (unsigned)D1) continue;
    for (int dy=0; dy<3; dy++){ int yy = 2*y-1+dy; if ((unsigned)yy >= (unsigned)H1) continue;
      for (int dx=0; dx<3; dx++){ int xc = 2*xx-1+dx; if ((unsigned)xc >= (unsigned)W1) continue;
        int ns = (zz*H1+yy)*W1+xc;
        int rr = I1[ns]; if (rr < 0) continue;
        const float* wk = wt + ((dz*3+dy)*3+dx)*16*32 + cout;
        const uint4* fr = (const uint4*)(fin + (size_t)rr*16);
        #pragma unroll
        for (int q=0; q<2; q++) acc8(acc, fr[q], wk + q*8*32, 32);
      }}}
  gout[(size_t)s*32 + cout] = f2bf(fmaxf(acc, 0.f));
}

// ---- generic subm conv on dense [site][C] grid (levels 2..4) ----
template<int CIN,int COUT,int DD,int HH,int WW>
__global__ void subm_dense_kernel(const unsigned short* __restrict__ gin,
                                  const float* __restrict__ msk,
                                  const int* __restrict__ list, const int* __restrict__ cnt, int cidx,
                                  const float* __restrict__ wt, const float* __restrict__ bias,
                                  unsigned short* __restrict__ gout){
  int t = blockIdx.x*BS + threadIdx.x;
  int row = t / COUT, cout = t % COUT;
  if (row >= cnt[cidx]) return;
  int s = list[row];
  int z = s/(HH*WW); int r = s - z*(HH*WW); int y = r/WW; int xx = r - y*WW;
  float acc = bias[cout];
  for (int dz=-1; dz<=1; dz++){ int zz=z+dz; if ((unsigned)zz >= (unsigned)DD) continue;
    for (int dy=-1; dy<=1; dy++){ int yy=y+dy; if ((unsigned)yy >= (unsigned)HH) continue;
      for (int dx=-1; dx<=1; dx++){ int xc=xx+dx; if ((unsigned)xc >= (unsigned)WW) continue;
        int ns = (zz*HH+yy)*WW+xc;
        if (msk[ns] == 0.f) continue;
        int k = ((dz+1)*3+(dy+1))*3+(dx+1);
        const float* wk = wt + k*CIN*COUT + cout;
        const uint4* fr = (const uint4*)(gin + (size_t)ns*CIN);
        #pragma unroll
        for (int q=0; q<CIN/8; q++) acc8(acc, fr[q], wk + q*8*COUT, COUT);
      }}}
  gout[(size_t)s*COUT + cout] = f2bf(fmaxf(acc, 0.f));
}

// ---- generic spconv stride-2 on dense [site][C] grid ----
template<int CIN,int COUT,int DI,int HI,int WI,int HOUT,int WOUT,int PZ,int PY,int PX>
__global__ void spconv_dense_kernel(const unsigned short* __restrict__ gin,
                                    const float* __restrict__ mskin,
                                    const int* __restrict__ list, const int* __restrict__ cnt, int cidx,
                                    const float* __restrict__ wt, const float* __restrict__ bias,
                                    unsigned short* __restrict__ gout){
  int t = blockIdx.x*BS + threadIdx.x;
  int row = t / COUT, cout = t % COUT;
  if (row >= cnt[cidx]) return;
  int s = list[row];
  int z = s/(HOUT*WOUT); int r = s - z*(HOUT*WOUT); int y = r/WOUT; int xx = r - y*WOUT;
  float acc = bias[cout];
  for (int dz=0; dz<3; dz++){ int zz = 2*z-PZ+dz; if ((unsigned)zz >= (unsigned)DI) continue;
    for (int dy=0; dy<3; dy++){ int yy = 2*y-PY+dy; if ((unsigned)yy >= (unsigned)HI) continue;
      for (int dx=0; dx<3; dx++){ int xc = 2*xx-PX+dx; if ((unsigned)xc >= (unsigned)WI) continue;
        int ns = (zz*HI+yy)*WI+xc;
        if (mskin[ns] == 0.f) continue;
        const float* wk = wt + ((dz*3+dy)*3+dx)*CIN*COUT + cout;
        const uint4* fr = (const uint4*)(gin + (size_t)ns*CIN);
        #pragma unroll
        for (int q=0; q<CIN/8; q++) acc8(acc, fr[q], wk + q*8*COUT, COUT);
      }}}
  gout[(size_t)s*COUT + cout] = f2bf(fmaxf(acc, 0.f));
}

// ---- final: spconv 64->128, k=(3,1,1), stride=(2,1,1), pad 0; write [1,256,25,22] f32 ----
__global__ void conv_out_kernel(const unsigned short* __restrict__ g4,
                                const float* __restrict__ m4,
                                const float* __restrict__ wt, const float* __restrict__ bias,
                                float* __restrict__ out){
  int t = blockIdx.x*BS + threadIdx.x;
  if (t >= 128*DOo*HOo*WOo) return;
  int cout = t & 127; int s = t >> 7;
  int d = s/(HOo*WOo); int r = s - d*(HOo*WOo); int h = r/WOo; int w = r - h*WOo;
  float res = 0.f;
  bool act = false;
  float acc = bias[cout];
  for (int dz=0; dz<3; dz++){
    int z4 = 2*d + dz;                       // always in [0, D4)
    int site = (z4*H4 + h)*W4 + w;
    if (m4[site] == 0.f) continue;
    act = true;
    const uint4* fr = (const uint4*)(g4 + (size_t)site*64);
    const float* wk = wt + dz*64*128 + cout;
    #pragma unroll
    for (int q=0; q<8; q++) acc8(acc, fr[q], wk + q*8*128, 128);
  }
  if (act) res = fmaxf(acc, 0.f);
  out[((cout*DOo + d)*HOo + h)*WOo + w] = res;
}

extern "C" void kernel_launch(void* const* d_in, const int* in_sizes, int n_in,
                              void* d_out, int out_size, void* d_ws, size_t ws_size,
                              hipStream_t stream){
  const float* x    = (const float*)d_in[0];
  const float* mask = (const float*)d_in[1];
  const float* w[12]; const float* bnp[12];
  for (int i=0;i<12;i++){ w[i]=(const float*)d_in[2+2*i]; bnp[i]=(const float*)d_in[3+2*i]; }

  char* base = (char*)d_ws; size_t off = 0;
  auto alloc = [&](size_t b)->void*{ void* p = base + off; off = (off + b + 255) & ~(size_t)255; return p; };

  int* cnt   = (int*)alloc(16);                         // [c1,c2,c3,c4]
  int* I1    = (int*)alloc((size_t)N1v*4);              // site -> compact row (-1 inactive)
  int* list1 = (int*)alloc((size_t)ROWS1*4);
  unsigned short* f1a = (unsigned short*)alloc((size_t)ROWS1*16*2);
  unsigned short* f1b = (unsigned short*)alloc((size_t)ROWS1*16*2);
  float* m2 = (float*)alloc((size_t)N2v*4);
  int* list2 = (int*)alloc((size_t)N2v*4);
  float* m3 = (float*)alloc((size_t)N3v*4);
  int* list3 = (int*)alloc((size_t)N3v*4);
  float* m4 = (float*)alloc((size_t)N4v*4);
  int* list4 = (int*)alloc((size_t)N4v*4);
  unsigned short* g2a = (unsigned short*)alloc((size_t)N2v*32*2);
  unsigned short* g2b = (unsigned short*)alloc((size_t)N2v*32*2);
  unsigned short* g3a = (unsigned short*)alloc((size_t)N3v*64*2);
  unsigned short* g3b = (unsigned short*)alloc((size_t)N3v*64*2);
  unsigned short* g4a = (unsigned short*)alloc((size_t)N4v*64*2);
  unsigned short* g4b = (unsigned short*)alloc((size_t)N4v*64*2);

  static const int Oa[12]={16,16,32,32,32,64,64,64,64,64,64,128};
  static const int Ia[12]={ 4,16,16,32,32,32,64,64,64,64,64, 64};
  static const int Ka[12]={27,27,27,27,27,27,27,27,27,27,27,  3};
  float* wt[12]; float* bs[12];
  for (int i=0;i<12;i++){
    wt[i] = (float*)alloc((size_t)Oa[i]*Ia[i]*Ka[i]*4);
    bs[i] = (float*)alloc((size_t)Oa[i]*4);
  }

  hipMemsetAsync(cnt, 0, 16, stream);
  hipMemsetAsync(I1, 0xFF, (size_t)N1v*4, stream);      // -1

  for (int i=0;i<12;i++){
    int tot = Oa[i]*Ia[i]*Ka[i];
    prep_weights<<<(tot+BS-1)/BS, BS, 0, stream>>>(w[i], bnp[i], wt[i], bs[i], Oa[i], Ia[i], Ka[i]);
  }

  build_list1_kernel<<<(N1v+BS-1)/BS, BS, 0, stream>>>(mask, I1, list1, cnt);

  // level 1 (two subm convs)
  subm_l0_kernel<<<(ROWS1*16)/BS, BS, 0, stream>>>(x, list1, cnt, wt[0], bs[0], f1a);
  subm_l1_kernel<<<(ROWS1*16)/BS, BS, 0, stream>>>(f1a, I1, list1, cnt, wt[1], bs[1], f1b);

  // level 1 -> 2
  build_mask_kernel<D1,H1,W1,D2,H2,W2,1,1,1><<<(N2v+BS-1)/BS, BS, 0, stream>>>(mask, m2, list2, cnt+1);
  spconv_l2_kernel<<<(N2v*32+BS-1)/BS, BS, 0, stream>>>(f1b, I1, list2, cnt, wt[2], bs[2], g2a);
  subm_dense_kernel<32,32,D2,H2,W2><<<(N2v*32+BS-1)/BS, BS, 0, stream>>>(g2a, m2, list2, cnt, 1, wt[3], bs[3], g2b);
  subm_dense_kernel<32,32,D2,H2,W2><<<(N2v*32+BS-1)/BS, BS, 0, stream>>>(g2b, m2, list2, cnt, 1, wt[4], bs[4], g2a);

  // level 2 -> 3
  build_mask_kernel<D2,H2,W2,D3,H3,W3,1,1,1><<<(N3v+BS-1)/BS, BS, 0, stream>>>(m2, m3, list3, cnt+2);
  spconv_dense_kernel<32,64,D2,H2,W2,H3,W3,1,1,1><<<(N3v*64+BS-1)/BS, BS, 0, stream>>>(g2a, m2, list3, cnt, 2, wt[5], bs[5], g3a);
  subm_dense_kernel<64,64,D3,H3,W3><<<(N3v*64+BS-1)/BS, BS, 0, stream>>>(g3a, m3, list3, cnt, 2, wt[6], bs[6], g3b);
  subm_dense_kernel<64,64,D3,H3,W3><<<(N3v*64+BS-1)/BS, BS, 0, stream>>>(g3b, m3, list3, cnt, 2, wt[7], bs[7], g3a);

  // level 3 -> 4 (pad (0,1,1))
  build_mask_kernel<D3,H3,W3,D4,H4,W4,0,1,1><<<(N4v+BS-1)/BS, BS, 0, stream>>>(m3, m4, list4, cnt+3);
  spconv_dense_kernel<64,64,D3,H3,W3,H4,W4,0,1,1><<<(N4v*64+BS-1)/BS, BS, 0, stream>>>(g3a, m3, list4, cnt, 3, wt[8], bs[8], g4a);
  subm_dense_kernel<64,64,D4,H4,W4><<<(N4v*64+BS-1)/BS, BS, 0, stream>>>(g4a, m4, list4, cnt, 3, wt[9], bs[9], g4b);
  subm_dense_kernel<64,64,D4,H4,W4><<<(N4v*64+BS-1)/BS, BS, 0, stream>>>(g4b, m4, list4, cnt, 3, wt[10], bs[10], g4a);

  // final spconv (3,1,1)/(2,1,1)/pad0 -> [1,256,25,22]
  conv_out_kernel<<<(128*DOo*HOo*WOo)/BS, BS, 0, stream>>>(g4a, m4, wt[11], bs[11], (float*)d_out);
}

// Round 2
// 807.059 us; speedup vs baseline: 2.5773x; 2.5773x over previous
//
#include <hip/hip_runtime.h>

#define BS 256

// ---- problem dims ----
constexpr int D1=41, H1=200, W1=176; constexpr int N1v=D1*H1*W1;   // 1,443,200
constexpr int D2=21, H2=100, W2=88;  constexpr int N2v=D2*H2*W2;   //   184,800
constexpr int D3=11, H3=50,  W3=44;  constexpr int N3v=D3*H3*W3;   //    24,200
constexpr int D4=5,  H4=25,  W4=22;  constexpr int N4v=D4*H4*W4;   //     2,750
constexpr int DOo=2, HOo=25, WOo=22;                                // out spatial
constexpr int ROWS1=65536;   // cap on level-1 active sites (actual ~29k at 2% density)

typedef __attribute__((ext_vector_type(8))) short bf16x8;
typedef __attribute__((ext_vector_type(4))) float f32x4;

// ---- bf16 helpers ----
__device__ __forceinline__ float bflo(unsigned int u){ return __uint_as_float(u<<16); }
__device__ __forceinline__ float bfhi(unsigned int u){ return __uint_as_float(u & 0xffff0000u); }
__device__ __forceinline__ unsigned short f2bf(float f){
  unsigned int x = __float_as_uint(f);
  x += 0x7fffu + ((x>>16)&1u);             // round-to-nearest-even
  return (unsigned short)(x>>16);
}
__device__ __forceinline__ void acc8(float& acc, uint4 p, const float* __restrict__ wk, int stride){
  acc = fmaf(bflo(p.x), wk[0*stride], acc);
  acc = fmaf(bfhi(p.x), wk[1*stride], acc);
  acc = fmaf(bflo(p.y), wk[2*stride], acc);
  acc = fmaf(bfhi(p.y), wk[3*stride], acc);
  acc = fmaf(bflo(p.z), wk[4*stride], acc);
  acc = fmaf(bfhi(p.z), wk[5*stride], acc);
  acc = fmaf(bflo(p.w), wk[6*stride], acc);
  acc = fmaf(bfhi(p.w), wk[7*stride], acc);
}

// ---- fold BN into weights, transpose to [ktap][ci][cout] (f32, scalar layers) ----
__global__ void prep_weights(const float* __restrict__ w, const float* __restrict__ bn,
                             float* __restrict__ wt, float* __restrict__ bias,
                             int O, int I, int K){
  int t = blockIdx.x*BS + threadIdx.x;
  int total = O*I*K;
  if (t >= total) return;
  int k = t % K; int rest = t / K; int ci = rest % I; int o = rest / I;
  float g = bn[o], b = bn[O+o], m = bn[2*O+o], v = bn[3*O+o];
  float scale = g * rsqrtf(v + 1e-3f);
  wt[(k*I+ci)*O + o] = w[(o*I+ci)*K + k] * scale;
  if (ci==0 && k==0) bias[o] = b - m*scale;
}

// ---- fold BN into weights, bf16 B^T layout [ktap][cout][cin] (MFMA layers) ----
__global__ void prep_weights_bt(const float* __restrict__ w, const float* __restrict__ bn,
                                unsigned short* __restrict__ wbt, float* __restrict__ bias,
                                int O, int I, int K){
  int t = blockIdx.x*BS + threadIdx.x;
  int total = O*I*K;
  if (t >= total) return;
  int k = t % K; int rest = t / K; int ci = rest % I; int o = rest / I;
  float g = bn[o], b = bn[O+o], m = bn[2*O+o], v = bn[3*O+o];
  float scale = g * rsqrtf(v + 1e-3f);
  wbt[((size_t)k*O + o)*I + ci] = f2bf(w[(o*I+ci)*K + k] * scale);
  if (ci==0 && k==0) bias[o] = b - m*scale;
}

// ---- level-1 active list + site->row index grid ----
__global__ void build_list1_kernel(const float* __restrict__ mask,
                                   int* __restrict__ I1, int* __restrict__ list1,
                                   int* __restrict__ cnt){
  int s = blockIdx.x*BS + threadIdx.x;
  if (s >= N1v) return;
  if (mask[s] > 0.f){
    int r = atomicAdd(cnt, 1);
    if (r < ROWS1){ list1[r] = s; I1[s] = r; }
  }
}

// ---- maxpool mask (k=3 s=2), build next-level mask + active list ----
template<int DI,int HI,int WI,int DOUT,int HOUT,int WOUT,int PZ,int PY,int PX>
__global__ void build_mask_kernel(const float* __restrict__ min_,
                                  float* __restrict__ mout,
                                  int* __restrict__ list, int* __restrict__ cnt1){
  int s = blockIdx.x*BS + threadIdx.x;
  if (s >= DOUT*HOUT*WOUT) return;
  int z = s/(HOUT*WOUT); int r = s - z*(HOUT*WOUT); int y = r/WOUT; int x = r - y*WOUT;
  bool act = false;
  for (int dz=0; dz<3 && !act; dz++){ int zz = 2*z - PZ + dz; if ((unsigned)zz >= (unsigned)DI) continue;
    for (int dy=0; dy<3 && !act; dy++){ int yy = 2*y - PY + dy; if ((unsigned)yy >= (unsigned)HI) continue;
      for (int dx=0; dx<3; dx++){ int xc = 2*x - PX + dx; if ((unsigned)xc >= (unsigned)WI) continue;
        if (min_[(zz*HI+yy)*WI+xc] > 0.f){ act = true; break; }
      }}}
  mout[s] = act ? 1.f : 0.f;
  if (act){ int r2 = atomicAdd(cnt1, 1); list[r2] = s; }
}

// ---- layer 0: subm conv 4->16 at level 1, dense f32 input x, compact bf16 output ----
__global__ void subm_l0_kernel(const float* __restrict__ x,
                               const int* __restrict__ list1, const int* __restrict__ cnt,
                               const float* __restrict__ wt, const float* __restrict__ bias,
                               unsigned short* __restrict__ fout){
  int t = blockIdx.x*BS + threadIdx.x;
  int row = t >> 4, cout = t & 15;
  if (row >= cnt[0]) return;
  int s = list1[row];
  int z = s/(H1*W1); int r = s - z*(H1*W1); int y = r/W1; int xx = r - y*W1;
  float acc = bias[cout];
  for (int dz=-1; dz<=1; dz++){ int zz=z+dz; if ((unsigned)zz >= (unsigned)D1) continue;
    for (int dy=-1; dy<=1; dy++){ int yy=y+dy; if ((unsigned)yy >= (unsigned)H1) continue;
      for (int dx=-1; dx<=1; dx++){ int xc=xx+dx; if ((unsigned)xc >= (unsigned)W1) continue;
        int ns = (zz*H1+yy)*W1+xc;
        int k = ((dz+1)*3+(dy+1))*3+(dx+1);
        const float* wk = wt + k*4*16 + cout;
        #pragma unroll
        for (int ci=0; ci<4; ci++) acc = fmaf(x[ci*N1v+ns], wk[ci*16], acc);
      }}}
  fout[row*16+cout] = f2bf(fmaxf(acc, 0.f));
}

// ---- layer 1: subm conv 16->16 at level 1, compact in/out via index grid ----
__global__ void subm_l1_kernel(const unsigned short* __restrict__ fin,
                               const int* __restrict__ I1,
                               const int* __restrict__ list1, const int* __restrict__ cnt,
                               const float* __restrict__ wt, const float* __restrict__ bias,
                               unsigned short* __restrict__ fout){
  int t = blockIdx.x*BS + threadIdx.x;
  int row = t >> 4, cout = t & 15;
  if (row >= cnt[0]) return;
  int s = list1[row];
  int z = s/(H1*W1); int r = s - z*(H1*W1); int y = r/W1; int xx = r - y*W1;
  float acc = bias[cout];
  for (int dz=-1; dz<=1; dz++){ int zz=z+dz; if ((unsigned)zz >= (unsigned)D1) continue;
    for (int dy=-1; dy<=1; dy++){ int yy=y+dy; if ((unsigned)yy >= (unsigned)H1) continue;
      for (int dx=-1; dx<=1; dx++){ int xc=xx+dx; if ((unsigned)xc >= (unsigned)W1) continue;
        int ns = (zz*H1+yy)*W1+xc;
        int rr = I1[ns]; if (rr < 0) continue;
        int k = ((dz+1)*3+(dy+1))*3+(dx+1);
        const float* wk = wt + k*16*16 + cout;
        const uint4* fr = (const uint4*)(fin + (size_t)rr*16);
        #pragma unroll
        for (int q=0; q<2; q++) acc8(acc, fr[q], wk + q*8*16, 16);
      }}}
  fout[row*16+cout] = f2bf(fmaxf(acc, 0.f));
}

// ---- layer 2: spconv 16->32 stride2 pad1, compact level-1 input -> dense level-2 out ----
__global__ void spconv_l2_kernel(const unsigned short* __restrict__ fin,
                                 const int* __restrict__ I1,
                                 const int* __restrict__ list2, const int* __restrict__ cnt,
                                 const float* __restrict__ wt, const float* __restrict__ bias,
                                 unsigned short* __restrict__ gout){
  int t = blockIdx.x*BS + threadIdx.x;
  int row = t >> 5, cout = t & 31;
  if (row >= cnt[1]) return;
  int s = list2[row];
  int z = s/(H2*W2); int r = s - z*(H2*W2); int y = r/W2; int xx = r - y*W2;
  float acc = bias[cout];
  for (int dz=0; dz<3; dz++){ int zz = 2*z-1+dz; if ((unsigned)zz >= (unsigned)D1) continue;
    for (int dy=0; dy<3; dy++){ int yy = 2*y-1+dy; if ((unsigned)yy >= (unsigned)H1) continue;
      for (int dx=0; dx<3; dx++){ int xc = 2*xx-1+dx; if ((unsigned)xc >= (unsigned)W1) continue;
        int ns = (zz*H1+yy)*W1+xc;
        int rr = I1[ns]; if (rr < 0) continue;
        const float* wk = wt + ((dz*3+dy)*3+dx)*16*32 + cout;
        const uint4* fr = (const uint4*)(fin + (size_t)rr*16);
        #pragma unroll
        for (int q=0; q<2; q++) acc8(acc, fr[q], wk + q*8*32, 32);
      }}}
  gout[(size_t)s*32 + cout] = f2bf(fmaxf(acc, 0.f));
}

// ---- MFMA implicit-gemm conv (subm if STR=1, spconv stride-2 if STR=2) ----
// Input grid gin: dense [site][CIN] bf16, ZERO at inactive sites.
// Output: writes only active list rows -> grid stays zero elsewhere (pre-memset).
// Block: 256 thr = 4 waves; 64 list-rows x COUT outputs per block.
template<int CIN,int COUT,int DI,int HI,int WI,int HO,int WO,int PZ,int PY,int PX,int STR>
__global__ __launch_bounds__(256)
void conv_mfma_kernel(const unsigned short* __restrict__ gin,
                      const int* __restrict__ list, const int* __restrict__ cnt, int cidx,
                      const unsigned short* __restrict__ wbt,   // [27][COUT][CIN] bf16
                      const float* __restrict__ bias,
                      unsigned short* __restrict__ gout){
  constexpr int AP = CIN + 8;              // padded LDS row stride (shorts) -> conflict-min
  constexpr int NT = COUT/16;              // N tiles
  constexpr int KT = CIN/32;               // K tiles per tap
  __shared__ __align__(16) unsigned short Alds[64*AP];
  __shared__ __align__(16) unsigned short Blds[COUT*AP];

  int nrows = cnt[cidx];
  int row0 = blockIdx.x*64;
  if (row0 >= nrows) return;

  int t = threadIdx.x;
  int lane = t & 63, wave = t >> 6;
  int r = t >> 2, part = t & 3;            // gather ownership: 4 threads per row
  int rowg = row0 + r;
  bool rvalid = rowg < nrows;
  int z=0, y=0, x=0;
  if (rvalid){
    int s = list[rowg];
    z = s/(HO*WO); int rem = s - z*(HO*WO); y = rem/WO; x = rem - y*WO;
  }

  f32x4 acc[NT];
  #pragma unroll
  for (int i=0;i<NT;i++) acc[i] = (f32x4){0.f,0.f,0.f,0.f};

  for (int k=0;k<27;k++){
    int dz = k/9, krem = k - dz*9, dy = krem/3, dx = krem - dy*3;
    __syncthreads();
    // stage A: 64 rows x CIN bf16 (gathered neighbor features)
    {
      constexpr int CH = CIN/4;            // shorts per (row,part)
      int zz = STR*z - PZ + dz, yy = STR*y - PY + dy, xx = STR*x - PX + dx;
      bool v = rvalid && (unsigned)zz < (unsigned)DI && (unsigned)yy < (unsigned)HI
                      && (unsigned)xx < (unsigned)WI;
      unsigned short* dst = Alds + r*AP + part*CH;
      if (v){
        const unsigned short* src = gin + (size_t)((zz*HI+yy)*WI+xx)*CIN + part*CH;
        #pragma unroll
        for (int q=0;q<CH/8;q++) ((uint4*)dst)[q] = ((const uint4*)src)[q];
      } else {
        #pragma unroll
        for (int q=0;q<CH/8;q++) ((uint4*)dst)[q] = (uint4){0,0,0,0};
      }
    }
    // stage B: COUT x CIN bf16 weights for this tap (B^T layout)
    {
      const unsigned short* src = wbt + (size_t)k*COUT*CIN;
      for (int e = t*4; e < COUT*CIN; e += BS*4){
        int n = e / CIN, c = e - n*CIN;
        *(uint2*)(Blds + n*AP + c) = *(const uint2*)(src + e);
      }
    }
    __syncthreads();
    // MFMA: per wave 16 rows x COUT
    int m = lane & 15, quad = lane >> 4;
    #pragma unroll
    for (int kt=0; kt<KT; kt++){
      bf16x8 a = *(const bf16x8*)(Alds + (wave*16 + m)*AP + kt*32 + quad*8);
      #pragma unroll
      for (int nt=0; nt<NT; nt++){
        bf16x8 b = *(const bf16x8*)(Blds + (nt*16 + m)*AP + kt*32 + quad*8);
        acc[nt] = __builtin_amdgcn_mfma_f32_16x16x32_bf16(a, b, acc[nt], 0, 0, 0);
      }
    }
  }

  // epilogue: C/D layout col=lane&15 (cout), row=(lane>>4)*4+reg (site)
  int m = lane & 15, quad = lane >> 4;
  #pragma unroll
  for (int nt=0; nt<NT; nt++){
    int cout = nt*16 + m;
    float bv = bias[cout];
    #pragma unroll
    for (int rg=0; rg<4; rg++){
      int rr = row0 + wave*16 + quad*4 + rg;
      if (rr < nrows){
        int s = list[rr];
        gout[(size_t)s*COUT + cout] = f2bf(fmaxf(acc[nt][rg] + bv, 0.f));
      }
    }
  }
}

// ---- final: spconv 64->128, k=(3,1,1), stride=(2,1,1), pad 0; write [1,256,25,22] f32 ----
__global__ void conv_out_kernel(const unsigned short* __restrict__ g4,
                                const float* __restrict__ m4,
                                const float* __restrict__ wt, const float* __restrict__ bias,
                                float* __restrict__ out){
  int t = blockIdx.x*BS + threadIdx.x;
  if (t >= 128*DOo*HOo*WOo) return;
  int cout = t & 127; int s = t >> 7;
  int d = s/(HOo*WOo); int r = s - d*(HOo*WOo); int h = r/WOo; int w = r - h*WOo;
  float res = 0.f;
  bool act = false;
  float acc = bias[cout];
  for (int dz=0; dz<3; dz++){
    int z4 = 2*d + dz;
    int site = (z4*H4 + h)*W4 + w;
    if (m4[site] == 0.f) continue;
    act = true;
    const uint4* fr = (const uint4*)(g4 + (size_t)site*64);
    const float* wk = wt + dz*64*128 + cout;
    #pragma unroll
    for (int q=0; q<8; q++) acc8(acc, fr[q], wk + q*8*128, 128);
  }
  if (act) res = fmaxf(acc, 0.f);
  out[((cout*DOo + d)*HOo + h)*WOo + w] = res;
}

extern "C" void kernel_launch(void* const* d_in, const int* in_sizes, int n_in,
                              void* d_out, int out_size, void* d_ws, size_t ws_size,
                              hipStream_t stream){
  const float* x    = (const float*)d_in[0];
  const float* mask = (const float*)d_in[1];
  const float* w[12]; const float* bnp[12];
  for (int i=0;i<12;i++){ w[i]=(const float*)d_in[2+2*i]; bnp[i]=(const float*)d_in[3+2*i]; }

  char* base = (char*)d_ws; size_t off = 0;
  auto alloc = [&](size_t b)->void*{ void* p = base + off; off = (off + b + 255) & ~(size_t)255; return p; };

  int* cnt   = (int*)alloc(16);                         // [c1,c2,c3,c4]
  int* I1    = (int*)alloc((size_t)N1v*4);              // site -> compact row (-1 inactive)
  int* list1 = (int*)alloc((size_t)ROWS1*4);
  unsigned short* f1a = (unsigned short*)alloc((size_t)ROWS1*16*2);
  unsigned short* f1b = (unsigned short*)alloc((size_t)ROWS1*16*2);
  float* m2 = (float*)alloc((size_t)N2v*4);
  int* list2 = (int*)alloc((size_t)N2v*4);
  float* m3 = (float*)alloc((size_t)N3v*4);
  int* list3 = (int*)alloc((size_t)N3v*4);
  float* m4 = (float*)alloc((size_t)N4v*4);
  int* list4 = (int*)alloc((size_t)N4v*4);
  unsigned short* g2a = (unsigned short*)alloc((size_t)N2v*32*2);
  unsigned short* g2b = (unsigned short*)alloc((size_t)N2v*32*2);
  unsigned short* g3a = (unsigned short*)alloc((size_t)N3v*64*2);
  unsigned short* g3b = (unsigned short*)alloc((size_t)N3v*64*2);
  unsigned short* g4a = (unsigned short*)alloc((size_t)N4v*64*2);
  unsigned short* g4b = (unsigned short*)alloc((size_t)N4v*64*2);

  static const int Oa[12]={16,16,32,32,32,64,64,64,64,64,64,128};
  static const int Ia[12]={ 4,16,16,32,32,32,64,64,64,64,64, 64};
  static const int Ka[12]={27,27,27,27,27,27,27,27,27,27,27,  3};
  // f32 [k][ci][cout] weights for scalar layers 0,1,2,11; bf16 B^T for 3..10
  float* wt[12]; float* bs[12]; unsigned short* wbt[12];
  for (int i=0;i<12;i++){
    bs[i] = (float*)alloc((size_t)Oa[i]*4);
    if (i<3 || i==11){ wt[i] = (float*)alloc((size_t)Oa[i]*Ia[i]*Ka[i]*4); wbt[i]=nullptr; }
    else { wbt[i] = (unsigned short*)alloc((size_t)Oa[i]*Ia[i]*Ka[i]*2); wt[i]=nullptr; }
  }

  hipMemsetAsync(cnt, 0, 16, stream);
  hipMemsetAsync(I1, 0xFF, (size_t)N1v*4, stream);      // -1
  // zero feature grids: MFMA gather reads them unconditionally -> inactive must be 0
  hipMemsetAsync(g2a, 0, (size_t)N2v*32*2, stream);
  hipMemsetAsync(g2b, 0, (size_t)N2v*32*2, stream);
  hipMemsetAsync(g3a, 0, (size_t)N3v*64*2, stream);
  hipMemsetAsync(g3b, 0, (size_t)N3v*64*2, stream);
  hipMemsetAsync(g4a, 0, (size_t)N4v*64*2, stream);
  hipMemsetAsync(g4b, 0, (size_t)N4v*64*2, stream);

  for (int i=0;i<12;i++){
    int tot = Oa[i]*Ia[i]*Ka[i];
    if (i<3 || i==11)
      prep_weights<<<(tot+BS-1)/BS, BS, 0, stream>>>(w[i], bnp[i], wt[i], bs[i], Oa[i], Ia[i], Ka[i]);
    else
      prep_weights_bt<<<(tot+BS-1)/BS, BS, 0, stream>>>(w[i], bnp[i], wbt[i], bs[i], Oa[i], Ia[i], Ka[i]);
  }

  build_list1_kernel<<<(N1v+BS-1)/BS, BS, 0, stream>>>(mask, I1, list1, cnt);

  // level 1 (two subm convs, scalar)
  subm_l0_kernel<<<(ROWS1*16)/BS, BS, 0, stream>>>(x, list1, cnt, wt[0], bs[0], f1a);
  subm_l1_kernel<<<(ROWS1*16)/BS, BS, 0, stream>>>(f1a, I1, list1, cnt, wt[1], bs[1], f1b);

  // level 1 -> 2 (scalar spconv into zeroed dense grid)
  build_mask_kernel<D1,H1,W1,D2,H2,W2,1,1,1><<<(N2v+BS-1)/BS, BS, 0, stream>>>(mask, m2, list2, cnt+1);
  spconv_l2_kernel<<<(N2v*32+BS-1)/BS, BS, 0, stream>>>(f1b, I1, list2, cnt, wt[2], bs[2], g2a);

  // level-2 subm convs (MFMA), 32ch
  {
    int nb = (N2v + 63)/64;
    conv_mfma_kernel<32,32,D2,H2,W2,H2,W2,1,1,1,1><<<nb, 256, 0, stream>>>(g2a, list2, cnt, 1, wbt[3], bs[3], g2b);
    conv_mfma_kernel<32,32,D2,H2,W2,H2,W2,1,1,1,1><<<nb, 256, 0, stream>>>(g2b, list2, cnt, 1, wbt[4], bs[4], g2a);
  }

  // level 2 -> 3 (MFMA spconv 32->64)
  build_mask_kernel<D2,H2,W2,D3,H3,W3,1,1,1><<<(N3v+BS-1)/BS, BS, 0, stream>>>(m2, m3, list3, cnt+2);
  {
    int nb = (N3v + 63)/64;
    conv_mfma_kernel<32,64,D2,H2,W2,H3,W3,1,1,1,2><<<nb, 256, 0, stream>>>(g2a, list3, cnt, 2, wbt[5], bs[5], g3a);
    conv_mfma_kernel<64,64,D3,H3,W3,H3,W3,1,1,1,1><<<nb, 256, 0, stream>>>(g3a, list3, cnt, 2, wbt[6], bs[6], g3b);
    conv_mfma_kernel<64,64,D3,H3,W3,H3,W3,1,1,1,1><<<nb, 256, 0, stream>>>(g3b, list3, cnt, 2, wbt[7], bs[7], g3a);
  }

  // level 3 -> 4 (MFMA spconv pad (0,1,1)) + level-4 subm convs
  build_mask_kernel<D3,H3,W3,D4,H4,W4,0,1,1><<<(N4v+BS-1)/BS, BS, 0, stream>>>(m3, m4, list4, cnt+3);
  {
    int nb = (N4v + 63)/64;
    conv_mfma_kernel<64,64,D3,H3,W3,H4,W4,0,1,1,2><<<nb, 256, 0, stream>>>(g3a, list4, cnt, 3, wbt[8], bs[8], g4a);
    conv_mfma_kernel<64,64,D4,H4,W4,H4,W4,1,1,1,1><<<nb, 256, 0, stream>>>(g4a, list4, cnt, 3, wbt[9], bs[9], g4b);
    conv_mfma_kernel<64,64,D4,H4,W4,H4,W4,1,1,1,1><<<nb, 256, 0, stream>>>(g4b, list4, cnt, 3, wbt[10], bs[10], g4a);
  }

  // final spconv (3,1,1)/(2,1,1)/pad0 -> [1,256,25,22]
  conv_out_kernel<<<(128*DOo*HOo*WOo)/BS, BS, 0, stream>>>(g4a, m4, wt[11], bs[11], (float*)d_out);
}

// Round 3
// 576.188 us; speedup vs baseline: 3.6100x; 1.4007x over previous
//
#include <hip/hip_runtime.h>

#define BS 256

// ---- problem dims ----
constexpr int D1=41, H1=200, W1=176; constexpr int N1v=D1*H1*W1;   // 1,443,200
constexpr int D2=21, H2=100, W2=88;  constexpr int N2v=D2*H2*W2;   //   184,800
constexpr int D3=11, H3=50,  W3=44;  constexpr int N3v=D3*H3*W3;   //    24,200
constexpr int D4=5,  H4=25,  W4=22;  constexpr int N4v=D4*H4*W4;   //     2,750
constexpr int DOo=2, HOo=25, WOo=22;                                // out spatial
constexpr int ROWS1=40960;   // cap on level-1 active sites (actual ~28.9k at 2% density)

typedef __attribute__((ext_vector_type(8))) short bf16x8;
typedef __attribute__((ext_vector_type(4))) float f32x4;

// ---- bf16 helpers ----
__device__ __forceinline__ float bflo(unsigned int u){ return __uint_as_float(u<<16); }
__device__ __forceinline__ float bfhi(unsigned int u){ return __uint_as_float(u & 0xffff0000u); }
__device__ __forceinline__ unsigned short f2bf(float f){
  unsigned int x = __float_as_uint(f);
  x += 0x7fffu + ((x>>16)&1u);             // round-to-nearest-even
  return (unsigned short)(x>>16);
}
__device__ __forceinline__ void acc8(float& acc, uint4 p, const float* __restrict__ wk, int stride){
  acc = fmaf(bflo(p.x), wk[0*stride], acc);
  acc = fmaf(bfhi(p.x), wk[1*stride], acc);
  acc = fmaf(bflo(p.y), wk[2*stride], acc);
  acc = fmaf(bfhi(p.y), wk[3*stride], acc);
  acc = fmaf(bflo(p.z), wk[4*stride], acc);
  acc = fmaf(bfhi(p.z), wk[5*stride], acc);
  acc = fmaf(bflo(p.w), wk[6*stride], acc);
  acc = fmaf(bfhi(p.w), wk[7*stride], acc);
}

// ---- fused BN-fold weight prep for all 12 layers ----
// mode 0: f32, layout [k][ci][o]           (layers 0, 11 — scalar kernels)
// mode 1: bf16 B^T, layout [k][o][ci]      (layers 3..10 — MFMA, K per tap = CIN)
// mode 2: bf16 tap-pair packed [p][o][32]  (layers 1, 2 — MFMA with K=2 taps x 16ci)
struct PrepArgs {
  const float* w[12]; const float* bn[12];
  void* dst[12]; float* bias[12];
  int O[12], I[12], K[12], mode[12];
  int off[13];
};
__global__ void prep_all(PrepArgs a){
  int t = blockIdx.x*BS + threadIdx.x;
  if (t >= a.off[12]) return;
  int li = 0;
  while (t >= a.off[li+1]) li++;
  int e = t - a.off[li];
  int O=a.O[li], I=a.I[li], K=a.K[li], mode=a.mode[li];
  const float* w = a.w[li]; const float* bn = a.bn[li];
  if (mode == 2){
    int p = e/(O*32); int rem = e - p*(O*32); int o = rem>>5; int kk = rem&31;
    int tap = 2*p + (kk>=16 ? 1 : 0); int ci = kk&15;
    float g=bn[o], b=bn[O+o], m=bn[2*O+o], v=bn[3*O+o];
    float sc = g*rsqrtf(v+1e-3f);
    float val = (tap < 27) ? w[(o*I+ci)*K + tap]*sc : 0.f;
    ((unsigned short*)a.dst[li])[e] = f2bf(val);
    if (p==0 && kk==0) a.bias[li][o] = b - m*sc;
  } else {
    int k = e % K; int rest = e / K; int ci = rest % I; int o = rest / I;
    float g=bn[o], b=bn[O+o], m=bn[2*O+o], v=bn[3*O+o];
    float sc = g*rsqrtf(v+1e-3f);
    float val = w[(o*I+ci)*K + k]*sc;
    if (mode == 0) ((float*)a.dst[li])[(k*I+ci)*O + o] = val;
    else ((unsigned short*)a.dst[li])[((size_t)k*O + o)*I + ci] = f2bf(val);
    if (ci==0 && k==0) a.bias[li][o] = b - m*sc;
  }
}

// ---- level-1 compaction: block-scan, ONE global atomic per block ----
// I1 sentinel: 0 = inactive, else row+1.  list order = block-sorted (good locality).
__global__ void build_list1_kernel(const float* __restrict__ mask,
                                   int* __restrict__ I1, int* __restrict__ list1,
                                   int* __restrict__ cnt){
  constexpr int PER = 16;
  __shared__ int sc[BS]; __shared__ int sbase;
  int b = blockIdx.x, t = threadIdx.x;
  int base_s = b*BS*PER;
  unsigned int bits = 0; int c = 0;
  #pragma unroll
  for (int i=0;i<PER;i++){
    int s = base_s + i*BS + t;
    bool act = (s < N1v) && (mask[s] > 0.f);
    bits |= (act?1u:0u) << i; c += act;
  }
  sc[t] = c;
  __syncthreads();
  for (int ofs=1; ofs<BS; ofs<<=1){
    int v = (t>=ofs) ? sc[t-ofs] : 0;
    __syncthreads();
    sc[t] += v;
    __syncthreads();
  }
  if (t == BS-1) sbase = atomicAdd(cnt, sc[t]);
  __syncthreads();
  int pos = sbase + sc[t] - c;
  #pragma unroll
  for (int i=0;i<PER;i++){
    if (bits & (1u<<i)){
      int s = base_s + i*BS + t;
      list1[pos] = s; I1[s] = pos+1; pos++;
    }
  }
}

// ---- maxpool mask (k=3 s=2) + compaction, block-scan atomics ----
template<int DI,int HI,int WI,int DOUT,int HOUT,int WOUT,int PZ,int PY,int PX>
__global__ void build_mask_kernel(const float* __restrict__ min_,
                                  float* __restrict__ mout,
                                  int* __restrict__ list, int* __restrict__ cnt1){
  constexpr int PER = 4;
  constexpr int N = DOUT*HOUT*WOUT;
  __shared__ int sc[BS]; __shared__ int sbase;
  int b = blockIdx.x, t = threadIdx.x;
  int base_s = b*BS*PER;
  unsigned int bits = 0; int c = 0;
  #pragma unroll
  for (int i=0;i<PER;i++){
    int s = base_s + i*BS + t;
    bool act = false;
    if (s < N){
      int z = s/(HOUT*WOUT); int r = s - z*(HOUT*WOUT); int y = r/WOUT; int x = r - y*WOUT;
      for (int dz=0; dz<3 && !act; dz++){ int zz = 2*z - PZ + dz; if ((unsigned)zz >= (unsigned)DI) continue;
        for (int dy=0; dy<3 && !act; dy++){ int yy = 2*y - PY + dy; if ((unsigned)yy >= (unsigned)HI) continue;
          for (int dx=0; dx<3; dx++){ int xc = 2*x - PX + dx; if ((unsigned)xc >= (unsigned)WI) continue;
            if (min_[(zz*HI+yy)*WI+xc] > 0.f){ act = true; break; }
          }}}
      mout[s] = act ? 1.f : 0.f;
    }
    bits |= (act?1u:0u) << i; c += act;
  }
  sc[t] = c;
  __syncthreads();
  for (int ofs=1; ofs<BS; ofs<<=1){
    int v = (t>=ofs) ? sc[t-ofs] : 0;
    __syncthreads();
    sc[t] += v;
    __syncthreads();
  }
  if (t == BS-1) sbase = atomicAdd(cnt1, sc[t]);
  __syncthreads();
  int pos = sbase + sc[t] - c;
  #pragma unroll
  for (int i=0;i<PER;i++){
    if (bits & (1u<<i)){
      int s = base_s + i*BS + t;
      list[pos] = s; pos++;
    }
  }
}

// ---- layer 0: subm conv 4->16 at level 1, dense f32 input x, compact bf16 output ----
__global__ void subm_l0_kernel(const float* __restrict__ x,
                               const int* __restrict__ list1, const int* __restrict__ cnt,
                               const float* __restrict__ wt, const float* __restrict__ bias,
                               unsigned short* __restrict__ fout){
  int t = blockIdx.x*BS + threadIdx.x;
  int row = t >> 4, cout = t & 15;
  if (row >= cnt[0]) return;
  int s = list1[row];
  int z = s/(H1*W1); int r = s - z*(H1*W1); int y = r/W1; int xx = r - y*W1;
  float acc = bias[cout];
  for (int dz=-1; dz<=1; dz++){ int zz=z+dz; if ((unsigned)zz >= (unsigned)D1) continue;
    for (int dy=-1; dy<=1; dy++){ int yy=y+dy; if ((unsigned)yy >= (unsigned)H1) continue;
      for (int dx=-1; dx<=1; dx++){ int xc=xx+dx; if ((unsigned)xc >= (unsigned)W1) continue;
        int ns = (zz*H1+yy)*W1+xc;
        int k = ((dz+1)*3+(dy+1))*3+(dx+1);
        const float* wk = wt + k*4*16 + cout;
        #pragma unroll
        for (int ci=0; ci<4; ci++) acc = fmaf(x[ci*N1v+ns], wk[ci*16], acc);
      }}}
  fout[row*16+cout] = f2bf(fmaxf(acc, 0.f));
}

// ---- level-1 MFMA conv: CIN=16, tap-pairs packed into K=32 (14 pairs, last padded) ----
// subm (STR=1, compact out) or spconv stride-2 (STR=2, dense out).
template<int COUT,int HO,int WO,int PZ,int PY,int PX,int STR,bool DENSE_OUT>
__global__ __launch_bounds__(256)
void conv_mfma_l1_kernel(const unsigned short* __restrict__ fin,   // compact [row][16]
                         const int* __restrict__ I1,
                         const int* __restrict__ list, const int* __restrict__ cnt, int cidx,
                         const unsigned short* __restrict__ wbt,   // [14][COUT][32]
                         const float* __restrict__ bias,
                         unsigned short* __restrict__ outp){
  constexpr int AP = 40;                   // padded LDS row stride (shorts)
  constexpr int NT = COUT/16;
  __shared__ __align__(16) unsigned short Alds[64*AP];
  __shared__ __align__(16) unsigned short Blds[COUT*AP];

  int nrows = cnt[cidx];
  int row0 = blockIdx.x*64;
  if (row0 >= nrows) return;

  int t = threadIdx.x;
  int lane = t & 63, wave = t >> 6;
  int r = t >> 2, part = t & 3;            // 4 threads per row; parts 0,1->tap even; 2,3->tap odd
  int rowg = row0 + r;
  bool rvalid = rowg < nrows;
  int z=0, y=0, x=0;
  if (rvalid){
    int s = list[rowg];
    z = s/(HO*WO); int rem = s - z*(HO*WO); y = rem/WO; x = rem - y*WO;
  }

  f32x4 acc[NT];
  #pragma unroll
  for (int i=0;i<NT;i++) acc[i] = (f32x4){0.f,0.f,0.f,0.f};

  for (int p=0;p<14;p++){
    __syncthreads();
    // stage A: 64 rows x 32 shorts (two taps of 16ci each)
    {
      int tap = 2*p + (part>>1);
      uint4 val = (uint4){0,0,0,0};
      if (rvalid && tap < 27){
        int dz = tap/9, rem = tap - dz*9, dy = rem/3, dx = rem - dy*3;
        int zz = STR*z - PZ + dz, yy = STR*y - PY + dy, xx = STR*x - PX + dx;
        if ((unsigned)zz < (unsigned)D1 && (unsigned)yy < (unsigned)H1 && (unsigned)xx < (unsigned)W1){
          int rr = I1[(zz*H1+yy)*W1+xx];
          if (rr > 0) val = ((const uint4*)(fin + (size_t)(rr-1)*16))[part&1];
        }
      }
      *(uint4*)(Alds + r*AP + (part>>1)*16 + (part&1)*8) = val;
    }
    // stage B: COUT x 32 shorts
    if (t < COUT*4)
      *(uint4*)(Blds + (t>>2)*AP + (t&3)*8) = ((const uint4*)(wbt + (size_t)p*COUT*32))[t];
    __syncthreads();
    int m = lane & 15, quad = lane >> 4;
    bf16x8 a = *(const bf16x8*)(Alds + (wave*16 + m)*AP + quad*8);
    #pragma unroll
    for (int nt=0; nt<NT; nt++){
      bf16x8 b = *(const bf16x8*)(Blds + (nt*16 + m)*AP + quad*8);
      acc[nt] = __builtin_amdgcn_mfma_f32_16x16x32_bf16(a, b, acc[nt], 0, 0, 0);
    }
  }

  int m = lane & 15, quad = lane >> 4;
  #pragma unroll
  for (int nt=0; nt<NT; nt++){
    int cout = nt*16 + m;
    float bv = bias[cout];
    #pragma unroll
    for (int rg=0; rg<4; rg++){
      int rr = row0 + wave*16 + quad*4 + rg;
      if (rr < nrows){
        float v = fmaxf(acc[nt][rg] + bv, 0.f);
        if (DENSE_OUT){
          int s = list[rr];
          outp[(size_t)s*COUT + cout] = f2bf(v);
        } else {
          outp[(size_t)rr*COUT + cout] = f2bf(v);
        }
      }
    }
  }
}

// ---- MFMA implicit-gemm conv on dense zeroed grids (levels 2..4) ----
template<int CIN,int COUT,int DI,int HI,int WI,int HO,int WO,int PZ,int PY,int PX,int STR>
__global__ __launch_bounds__(256)
void conv_mfma_kernel(const unsigned short* __restrict__ gin,
                      const int* __restrict__ list, const int* __restrict__ cnt, int cidx,
                      const unsigned short* __restrict__ wbt,   // [27][COUT][CIN] bf16
                      const float* __restrict__ bias,
                      unsigned short* __restrict__ gout){
  constexpr int AP = CIN + 8;
  constexpr int NT = COUT/16;
  constexpr int KT = CIN/32;
  __shared__ __align__(16) unsigned short Alds[64*AP];
  __shared__ __align__(16) unsigned short Blds[COUT*AP];

  int nrows = cnt[cidx];
  int row0 = blockIdx.x*64;
  if (row0 >= nrows) return;

  int t = threadIdx.x;
  int lane = t & 63, wave = t >> 6;
  int r = t >> 2, part = t & 3;
  int rowg = row0 + r;
  bool rvalid = rowg < nrows;
  int z=0, y=0, x=0;
  if (rvalid){
    int s = list[rowg];
    z = s/(HO*WO); int rem = s - z*(HO*WO); y = rem/WO; x = rem - y*WO;
  }

  f32x4 acc[NT];
  #pragma unroll
  for (int i=0;i<NT;i++) acc[i] = (f32x4){0.f,0.f,0.f,0.f};

  for (int k=0;k<27;k++){
    int dz = k/9, krem = k - dz*9, dy = krem/3, dx = krem - dy*3;
    __syncthreads();
    {
      constexpr int CH = CIN/4;
      int zz = STR*z - PZ + dz, yy = STR*y - PY + dy, xx = STR*x - PX + dx;
      bool v = rvalid && (unsigned)zz < (unsigned)DI && (unsigned)yy < (unsigned)HI
                      && (unsigned)xx < (unsigned)WI;
      unsigned short* dst = Alds + r*AP + part*CH;
      if (v){
        const unsigned short* src = gin + (size_t)((zz*HI+yy)*WI+xx)*CIN + part*CH;
        #pragma unroll
        for (int q=0;q<CH/8;q++) ((uint4*)dst)[q] = ((const uint4*)src)[q];
      } else {
        #pragma unroll
        for (int q=0;q<CH/8;q++) ((uint4*)dst)[q] = (uint4){0,0,0,0};
      }
    }
    {
      const unsigned short* src = wbt + (size_t)k*COUT*CIN;
      for (int e = t*4; e < COUT*CIN; e += BS*4){
        int n = e / CIN, c = e - n*CIN;
        *(uint2*)(Blds + n*AP + c) = *(const uint2*)(src + e);
      }
    }
    __syncthreads();
    int m = lane & 15, quad = lane >> 4;
    #pragma unroll
    for (int kt=0; kt<KT; kt++){
      bf16x8 a = *(const bf16x8*)(Alds + (wave*16 + m)*AP + kt*32 + quad*8);
      #pragma unroll
      for (int nt=0; nt<NT; nt++){
        bf16x8 b = *(const bf16x8*)(Blds + (nt*16 + m)*AP + kt*32 + quad*8);
        acc[nt] = __builtin_amdgcn_mfma_f32_16x16x32_bf16(a, b, acc[nt], 0, 0, 0);
      }
    }
  }

  int m = lane & 15, quad = lane >> 4;
  #pragma unroll
  for (int nt=0; nt<NT; nt++){
    int cout = nt*16 + m;
    float bv = bias[cout];
    #pragma unroll
    for (int rg=0; rg<4; rg++){
      int rr = row0 + wave*16 + quad*4 + rg;
      if (rr < nrows){
        int s = list[rr];
        gout[(size_t)s*COUT + cout] = f2bf(fmaxf(acc[nt][rg] + bv, 0.f));
      }
    }
  }
}

// ---- final: spconv 64->128, k=(3,1,1), stride=(2,1,1), pad 0; write [1,256,25,22] f32 ----
__global__ void conv_out_kernel(const unsigned short* __restrict__ g4,
                                const float* __restrict__ m4,
                                const float* __restrict__ wt, const float* __restrict__ bias,
                                float* __restrict__ out){
  int t = blockIdx.x*BS + threadIdx.x;
  if (t >= 128*DOo*HOo*WOo) return;
  int cout = t & 127; int s = t >> 7;
  int d = s/(HOo*WOo); int r = s - d*(HOo*WOo); int h = r/WOo; int w = r - h*WOo;
  float res = 0.f;
  bool act = false;
  float acc = bias[cout];
  for (int dz=0; dz<3; dz++){
    int z4 = 2*d + dz;
    int site = (z4*H4 + h)*W4 + w;
    if (m4[site] == 0.f) continue;
    act = true;
    const uint4* fr = (const uint4*)(g4 + (size_t)site*64);
    const float* wk = wt + dz*64*128 + cout;
    #pragma unroll
    for (int q=0; q<8; q++) acc8(acc, fr[q], wk + q*8*128, 128);
  }
  if (act) res = fmaxf(acc, 0.f);
  out[((cout*DOo + d)*HOo + h)*WOo + w] = res;
}

extern "C" void kernel_launch(void* const* d_in, const int* in_sizes, int n_in,
                              void* d_out, int out_size, void* d_ws, size_t ws_size,
                              hipStream_t stream){
  const float* x    = (const float*)d_in[0];
  const float* mask = (const float*)d_in[1];
  const float* w[12]; const float* bnp[12];
  for (int i=0;i<12;i++){ w[i]=(const float*)d_in[2+2*i]; bnp[i]=(const float*)d_in[3+2*i]; }

  char* base = (char*)d_ws; size_t off = 0;
  auto alloc = [&](size_t b)->void*{ void* p = base + off; off = (off + b + 255) & ~(size_t)255; return p; };

  // --- region that must be zeroed every call (one memset covers [0, zero_bytes)) ---
  int* cnt   = (int*)alloc(16);                         // [c1,c2,c3,c4]
  int* I1    = (int*)alloc((size_t)N1v*4);              // site -> row+1 (0 = inactive)
  unsigned short* g2a = (unsigned short*)alloc((size_t)N2v*32*2);
  unsigned short* g2b = (unsigned short*)alloc((size_t)N2v*32*2);
  unsigned short* g3a = (unsigned short*)alloc((size_t)N3v*64*2);
  unsigned short* g3b = (unsigned short*)alloc((size_t)N3v*64*2);
  unsigned short* g4a = (unsigned short*)alloc((size_t)N4v*64*2);
  unsigned short* g4b = (unsigned short*)alloc((size_t)N4v*64*2);
  size_t zero_bytes = off;
  // --- fully-overwritten-before-read buffers ---
  int* list1 = (int*)alloc((size_t)ROWS1*4);
  unsigned short* f1a = (unsigned short*)alloc((size_t)ROWS1*16*2);
  unsigned short* f1b = (unsigned short*)alloc((size_t)ROWS1*16*2);
  float* m2 = (float*)alloc((size_t)N2v*4);
  int* list2 = (int*)alloc((size_t)N2v*4);
  float* m3 = (float*)alloc((size_t)N3v*4);
  int* list3 = (int*)alloc((size_t)N3v*4);
  float* m4 = (float*)alloc((size_t)N4v*4);
  int* list4 = (int*)alloc((size_t)N4v*4);

  static const int Oa[12]={16,16,32,32,32,64,64,64,64,64,64,128};
  static const int Ia[12]={ 4,16,16,32,32,32,64,64,64,64,64, 64};
  static const int Ka[12]={27,27,27,27,27,27,27,27,27,27,27,  3};
  static const int Ma[12]={ 0, 2, 2, 1, 1, 1, 1, 1, 1, 1, 1,  0};  // prep mode
  float* wt[12]; float* bs[12]; unsigned short* wbt[12];
  for (int i=0;i<12;i++){
    bs[i] = (float*)alloc((size_t)Oa[i]*4);
    wt[i]=nullptr; wbt[i]=nullptr;
    if (Ma[i]==0)      wt[i]  = (float*)alloc((size_t)Oa[i]*Ia[i]*Ka[i]*4);
    else if (Ma[i]==1) wbt[i] = (unsigned short*)alloc((size_t)Ka[i]*Oa[i]*Ia[i]*2);
    else               wbt[i] = (unsigned short*)alloc((size_t)14*Oa[i]*32*2);
  }

  hipMemsetAsync(base, 0, zero_bytes, stream);

  // fused weight prep
  PrepArgs pa;
  pa.off[0] = 0;
  for (int i=0;i<12;i++){
    pa.w[i]=w[i]; pa.bn[i]=bnp[i]; pa.bias[i]=bs[i];
    pa.O[i]=Oa[i]; pa.I[i]=Ia[i]; pa.K[i]=Ka[i]; pa.mode[i]=Ma[i];
    pa.dst[i] = (Ma[i]==0) ? (void*)wt[i] : (void*)wbt[i];
    int tot = (Ma[i]==2) ? 14*Oa[i]*32 : Oa[i]*Ia[i]*Ka[i];
    pa.off[i+1] = pa.off[i] + tot;
  }
  prep_all<<<(pa.off[12]+BS-1)/BS, BS, 0, stream>>>(pa);

  // level-1 compaction (block-scan, 353 atomics total)
  build_list1_kernel<<<(N1v + BS*16 - 1)/(BS*16), BS, 0, stream>>>(mask, I1, list1, cnt);

  // level 1: subm 4->16 scalar, then subm 16->16 MFMA
  subm_l0_kernel<<<(ROWS1*16)/BS, BS, 0, stream>>>(x, list1, cnt, wt[0], bs[0], f1a);
  conv_mfma_l1_kernel<16,H1,W1,1,1,1,1,false><<<ROWS1/64, 256, 0, stream>>>
      (f1a, I1, list1, cnt, 0, wbt[1], bs[1], f1b);

  // level 1 -> 2: mask + MFMA spconv 16->32 into zeroed dense grid
  build_mask_kernel<D1,H1,W1,D2,H2,W2,1,1,1><<<(N2v + BS*4 - 1)/(BS*4), BS, 0, stream>>>(mask, m2, list2, cnt+1);
  conv_mfma_l1_kernel<32,H2,W2,1,1,1,2,true><<<(N2v+63)/64, 256, 0, stream>>>
      (f1b, I1, list2, cnt, 1, wbt[2], bs[2], g2a);

  // level-2 subm convs (MFMA), 32ch
  {
    int nb = (N2v + 63)/64;
    conv_mfma_kernel<32,32,D2,H2,W2,H2,W2,1,1,1,1><<<nb, 256, 0, stream>>>(g2a, list2, cnt, 1, wbt[3], bs[3], g2b);
    conv_mfma_kernel<32,32,D2,H2,W2,H2,W2,1,1,1,1><<<nb, 256, 0, stream>>>(g2b, list2, cnt, 1, wbt[4], bs[4], g2a);
  }

  // level 2 -> 3 (MFMA spconv 32->64) + level-3 subm convs
  build_mask_kernel<D2,H2,W2,D3,H3,W3,1,1,1><<<(N3v + BS*4 - 1)/(BS*4), BS, 0, stream>>>(m2, m3, list3, cnt+2);
  {
    int nb = (N3v + 63)/64;
    conv_mfma_kernel<32,64,D2,H2,W2,H3,W3,1,1,1,2><<<nb, 256, 0, stream>>>(g2a, list3, cnt, 2, wbt[5], bs[5], g3a);
    conv_mfma_kernel<64,64,D3,H3,W3,H3,W3,1,1,1,1><<<nb, 256, 0, stream>>>(g3a, list3, cnt, 2, wbt[6], bs[6], g3b);
    conv_mfma_kernel<64,64,D3,H3,W3,H3,W3,1,1,1,1><<<nb, 256, 0, stream>>>(g3b, list3, cnt, 2, wbt[7], bs[7], g3a);
  }

  // level 3 -> 4 (MFMA spconv pad (0,1,1)) + level-4 subm convs
  build_mask_kernel<D3,H3,W3,D4,H4,W4,0,1,1><<<(N4v + BS*4 - 1)/(BS*4), BS, 0, stream>>>(m3, m4, list4, cnt+3);
  {
    int nb = (N4v + 63)/64;
    conv_mfma_kernel<64,64,D3,H3,W3,H4,W4,0,1,1,2><<<nb, 256, 0, stream>>>(g3a, list4, cnt, 3, wbt[8], bs[8], g4a);
    conv_mfma_kernel<64,64,D4,H4,W4,H4,W4,1,1,1,1><<<nb, 256, 0, stream>>>(g4a, list4, cnt, 3, wbt[9], bs[9], g4b);
    conv_mfma_kernel<64,64,D4,H4,W4,H4,W4,1,1,1,1><<<nb, 256, 0, stream>>>(g4b, list4, cnt, 3, wbt[10], bs[10], g4a);
  }

  // final spconv (3,1,1)/(2,1,1)/pad0 -> [1,256,25,22]
  conv_out_kernel<<<(128*DOo*HOo*WOo)/BS, BS, 0, stream>>>(g4a, m4, wt[11], bs[11], (float*)d_out);
}

// Round 4
// 438.855 us; speedup vs baseline: 4.7397x; 1.3129x over previous
//
#include <hip/hip_runtime.h>

#define BS 256

// ---- problem dims ----
constexpr int D1=41, H1=200, W1=176; constexpr int N1v=D1*H1*W1;   // 1,443,200
constexpr int D2=21, H2=100, W2=88;  constexpr int N2v=D2*H2*W2;   //   184,800
constexpr int D3=11, H3=50,  W3=44;  constexpr int N3v=D3*H3*W3;   //    24,200
constexpr int D4=5,  H4=25,  W4=22;  constexpr int N4v=D4*H4*W4;   //     2,750
constexpr int DOo=2, HOo=25, WOo=22;                                // out spatial
constexpr int ROWS1=40960;   // cap on level-1 active sites (actual ~28.9k)

typedef __attribute__((ext_vector_type(8))) short bf16x8;
typedef __attribute__((ext_vector_type(4))) float f32x4;

// ---- bf16 helpers ----
__device__ __forceinline__ float bflo(unsigned int u){ return __uint_as_float(u<<16); }
__device__ __forceinline__ float bfhi(unsigned int u){ return __uint_as_float(u & 0xffff0000u); }
__device__ __forceinline__ unsigned short f2bf(float f){
  unsigned int x = __float_as_uint(f);
  x += 0x7fffu + ((x>>16)&1u);             // round-to-nearest-even
  return (unsigned short)(x>>16);
}
__device__ __forceinline__ void acc8(float& acc, uint4 p, const float* __restrict__ wk, int stride){
  acc = fmaf(bflo(p.x), wk[0*stride], acc);
  acc = fmaf(bfhi(p.x), wk[1*stride], acc);
  acc = fmaf(bflo(p.y), wk[2*stride], acc);
  acc = fmaf(bfhi(p.y), wk[3*stride], acc);
  acc = fmaf(bflo(p.z), wk[4*stride], acc);
  acc = fmaf(bfhi(p.z), wk[5*stride], acc);
  acc = fmaf(bflo(p.w), wk[6*stride], acc);
  acc = fmaf(bfhi(p.w), wk[7*stride], acc);
}

// ---- fused BN-fold weight prep for all 12 layers ----
// mode 0: f32, layout [k][ci][o]                 (layers 0, 11 — scalar kernels)
// mode 2: bf16 tap-pair packed [p][o][32]        (layers 1, 2 — l1 MFMA, K=2 taps x 16ci)
// mode 3: bf16 supertap [dzdy][o][dx*CIN+ci]     (layers 3..10 — dense MFMA, K=3*CIN)
struct PrepArgs {
  const float* w[12]; const float* bn[12];
  void* dst[12]; float* bias[12];
  int O[12], I[12], K[12], mode[12];
  int off[13];
};
__global__ void prep_all(PrepArgs a){
  int t = blockIdx.x*BS + threadIdx.x;
  if (t >= a.off[12]) return;
  int li = 0;
  while (t >= a.off[li+1]) li++;
  int e = t - a.off[li];
  int O=a.O[li], I=a.I[li], K=a.K[li], mode=a.mode[li];
  const float* w = a.w[li]; const float* bn = a.bn[li];
  if (mode == 2){
    int p = e/(O*32); int rem = e - p*(O*32); int o = rem>>5; int kk = rem&31;
    int tap = 2*p + (kk>=16 ? 1 : 0); int ci = kk&15;
    float g=bn[o], b=bn[O+o], m=bn[2*O+o], v=bn[3*O+o];
    float sc = g*rsqrtf(v+1e-3f);
    float val = (tap < 27) ? w[(o*I+ci)*K + tap]*sc : 0.f;
    ((unsigned short*)a.dst[li])[e] = f2bf(val);
    if (p==0 && kk==0) a.bias[li][o] = b - m*sc;
  } else if (mode == 3){
    int ci = e % I; int tmp = e / I; int dx = tmp % 3; tmp /= 3; int o = tmp % O; int g9 = tmp / O;
    float g=bn[o], b=bn[O+o], m=bn[2*O+o], v=bn[3*O+o];
    float sc = g*rsqrtf(v+1e-3f);
    int tap = g9*3 + dx;
    ((unsigned short*)a.dst[li])[e] = f2bf(w[(o*I+ci)*27 + tap]*sc);
    if (g9==0 && dx==0 && ci==0) a.bias[li][o] = b - m*sc;
  } else {
    int k = e % K; int rest = e / K; int ci = rest % I; int o = rest / I;
    float g=bn[o], b=bn[O+o], m=bn[2*O+o], v=bn[3*O+o];
    float sc = g*rsqrtf(v+1e-3f);
    ((float*)a.dst[li])[(k*I+ci)*O + o] = w[(o*I+ci)*K + k]*sc;
    if (ci==0 && k==0) a.bias[li][o] = b - m*sc;
  }
}

// ---- level-1 compaction: block-scan, ONE global atomic per block ----
__global__ void build_list1_kernel(const float* __restrict__ mask,
                                   int* __restrict__ I1, int* __restrict__ list1,
                                   int* __restrict__ cnt){
  constexpr int PER = 16;
  __shared__ int sc[BS]; __shared__ int sbase;
  int b = blockIdx.x, t = threadIdx.x;
  int base_s = b*BS*PER;
  unsigned int bits = 0; int c = 0;
  #pragma unroll
  for (int i=0;i<PER;i++){
    int s = base_s + i*BS + t;
    bool act = (s < N1v) && (mask[s] > 0.f);
    bits |= (act?1u:0u) << i; c += act;
  }
  sc[t] = c;
  __syncthreads();
  for (int ofs=1; ofs<BS; ofs<<=1){
    int v = (t>=ofs) ? sc[t-ofs] : 0;
    __syncthreads();
    sc[t] += v;
    __syncthreads();
  }
  if (t == BS-1) sbase = atomicAdd(cnt, sc[t]);
  __syncthreads();
  int pos = sbase + sc[t] - c;
  #pragma unroll
  for (int i=0;i<PER;i++){
    if (bits & (1u<<i)){
      int s = base_s + i*BS + t;
      list1[pos] = s; I1[s] = pos+1; pos++;
    }
  }
}

// ---- maxpool mask (k=3 s=2) + compaction ----
template<int DI,int HI,int WI,int DOUT,int HOUT,int WOUT,int PZ,int PY,int PX>
__global__ void build_mask_kernel(const float* __restrict__ min_,
                                  float* __restrict__ mout,
                                  int* __restrict__ list, int* __restrict__ cnt1){
  constexpr int PER = 4;
  constexpr int N = DOUT*HOUT*WOUT;
  __shared__ int sc[BS]; __shared__ int sbase;
  int b = blockIdx.x, t = threadIdx.x;
  int base_s = b*BS*PER;
  unsigned int bits = 0; int c = 0;
  #pragma unroll
  for (int i=0;i<PER;i++){
    int s = base_s + i*BS + t;
    bool act = false;
    if (s < N){
      int z = s/(HOUT*WOUT); int r = s - z*(HOUT*WOUT); int y = r/WOUT; int x = r - y*WOUT;
      for (int dz=0; dz<3 && !act; dz++){ int zz = 2*z - PZ + dz; if ((unsigned)zz >= (unsigned)DI) continue;
        for (int dy=0; dy<3 && !act; dy++){ int yy = 2*y - PY + dy; if ((unsigned)yy >= (unsigned)HI) continue;
          for (int dx=0; dx<3; dx++){ int xc = 2*x - PX + dx; if ((unsigned)xc >= (unsigned)WI) continue;
            if (min_[(zz*HI+yy)*WI+xc] > 0.f){ act = true; break; }
          }}}
      mout[s] = act ? 1.f : 0.f;
    }
    bits |= (act?1u:0u) << i; c += act;
  }
  sc[t] = c;
  __syncthreads();
  for (int ofs=1; ofs<BS; ofs<<=1){
    int v = (t>=ofs) ? sc[t-ofs] : 0;
    __syncthreads();
    sc[t] += v;
    __syncthreads();
  }
  if (t == BS-1) sbase = atomicAdd(cnt1, sc[t]);
  __syncthreads();
  int pos = sbase + sc[t] - c;
  #pragma unroll
  for (int i=0;i<PER;i++){
    if (bits & (1u<<i)){
      int s = base_s + i*BS + t;
      list[pos] = s; pos++;
    }
  }
}

// ---- layer 0: subm conv 4->16 at level 1, dense f32 input x, compact bf16 output ----
__global__ void subm_l0_kernel(const float* __restrict__ x,
                               const int* __restrict__ list1, const int* __restrict__ cnt,
                               const float* __restrict__ wt, const float* __restrict__ bias,
                               unsigned short* __restrict__ fout){
  int t = blockIdx.x*BS + threadIdx.x;
  int row = t >> 4, cout = t & 15;
  if (row >= cnt[0]) return;
  int s = list1[row];
  int z = s/(H1*W1); int r = s - z*(H1*W1); int y = r/W1; int xx = r - y*W1;
  float acc = bias[cout];
  for (int dz=-1; dz<=1; dz++){ int zz=z+dz; if ((unsigned)zz >= (unsigned)D1) continue;
    for (int dy=-1; dy<=1; dy++){ int yy=y+dy; if ((unsigned)yy >= (unsigned)H1) continue;
      for (int dx=-1; dx<=1; dx++){ int xc=xx+dx; if ((unsigned)xc >= (unsigned)W1) continue;
        int ns = (zz*H1+yy)*W1+xc;
        int k = ((dz+1)*3+(dy+1))*3+(dx+1);
        const float* wk = wt + k*4*16 + cout;
        #pragma unroll
        for (int ci=0; ci<4; ci++) acc = fmaf(x[ci*N1v+ns], wk[ci*16], acc);
      }}}
  fout[row*16+cout] = f2bf(fmaxf(acc, 0.f));
}

// ---- level-1 MFMA conv, A direct-from-global, B staged ONCE in LDS, no loop barriers ----
// CIN=16, tap-pairs K=32 (14 pairs, last zero-padded).
template<int COUT,int HO,int WO,int PZ,int PY,int PX,int STR,bool DENSE_OUT>
__global__ __launch_bounds__(256)
void conv_mfma_l1_kernel(const unsigned short* __restrict__ fin,   // compact [row][16]
                         const int* __restrict__ I1,
                         const int* __restrict__ list, const int* __restrict__ cnt, int cidx,
                         const unsigned short* __restrict__ wbt,   // [14][COUT][32]
                         const float* __restrict__ bias,
                         unsigned short* __restrict__ outp){
  constexpr int BP = 40;                   // padded LDS row stride (shorts)
  constexpr int NT = COUT/16;
  __shared__ __align__(16) unsigned short B[14*COUT*BP];

  int nrows = cnt[cidx];
  int row0 = blockIdx.x*64;
  if (row0 >= nrows) return;

  int t = threadIdx.x;
  int lane = t & 63, wave = t >> 6;
  int m = lane & 15, quad = lane >> 4;

  // stage all weights once
  constexpr int TOT = 14*COUT*32;
  for (int e = t*8; e < TOT; e += BS*8){
    int n = e >> 5, c = e & 31;
    *(uint4*)(&B[n*BP + c]) = *(const uint4*)(wbt + e);
  }

  int row = row0 + wave*16 + m;
  bool rv = row < nrows;
  int z=0, y=0, x=0;
  {
    int s = list[rv ? row : row0];
    z = s/(HO*WO); int rem = s - z*(HO*WO); y = rem/WO; x = rem - y*WO;
  }
  __syncthreads();

  f32x4 acc[NT];
  #pragma unroll
  for (int i=0;i<NT;i++) acc[i] = (f32x4){0.f,0.f,0.f,0.f};

  #pragma unroll
  for (int p=0;p<14;p++){
    int tap = 2*p + (quad>>1);             // quads 0,1 -> even tap; 2,3 -> odd tap
    bf16x8 a = (bf16x8){0,0,0,0,0,0,0,0};
    if (rv && tap < 27){
      int dz = tap/9, rem = tap - dz*9, dy = rem/3, dx = rem - dy*3;
      int zz = STR*z - PZ + dz, yy = STR*y - PY + dy, xx = STR*x - PX + dx;
      if ((unsigned)zz < (unsigned)D1 && (unsigned)yy < (unsigned)H1 && (unsigned)xx < (unsigned)W1){
        int rr = I1[(zz*H1+yy)*W1+xx];
        if (rr > 0) a = *(const bf16x8*)(fin + (size_t)(rr-1)*16 + (quad&1)*8);
      }
    }
    #pragma unroll
    for (int nt=0; nt<NT; nt++){
      bf16x8 b = *(const bf16x8*)(&B[(p*COUT + nt*16 + m)*BP + quad*8]);
      acc[nt] = __builtin_amdgcn_mfma_f32_16x16x32_bf16(a, b, acc[nt], 0, 0, 0);
    }
  }

  #pragma unroll
  for (int nt=0; nt<NT; nt++){
    int cout = nt*16 + m;
    float bv = bias[cout];
    #pragma unroll
    for (int rg=0; rg<4; rg++){
      int rw = row0 + wave*16 + quad*4 + rg;
      if (rw < nrows){
        float v = fmaxf(acc[nt][rg] + bv, 0.f);
        if (DENSE_OUT){
          int s = list[rw];
          outp[(size_t)s*COUT + cout] = f2bf(v);
        } else {
          outp[(size_t)rw*COUT + cout] = f2bf(v);
        }
      }
    }
  }
}

// ---- dense-grid MFMA conv, A direct-from-global (x-contiguous supertaps K=3*CIN),
//      B double-buffered in LDS, ONE barrier per supertap (9 total) ----
template<int CIN,int COUT,int DI,int HI,int WI,int HO,int WO,int PZ,int PY,int PX,int STR>
__global__ __launch_bounds__(256)
void conv_mfma2_kernel(const unsigned short* __restrict__ gin,
                       const int* __restrict__ list, const int* __restrict__ cnt, int cidx,
                       const unsigned short* __restrict__ wg,    // [9][COUT][3*CIN]
                       const float* __restrict__ bias,
                       unsigned short* __restrict__ gout){
  constexpr int KW = 3*CIN;                // K per supertap
  constexpr int BP = KW + 8;               // padded LDS row (shorts); row stride 16B-aligned
  constexpr int NT = COUT/16;
  constexpr int KT = KW/32;
  constexpr int PREN = (COUT*KW + BS*8 - 1)/(BS*8);
  __shared__ __align__(16) unsigned short B[2][COUT*BP];

  int nrows = cnt[cidx];
  int row0 = blockIdx.x*64;
  if (row0 >= nrows) return;

  int t = threadIdx.x;
  int lane = t & 63, wave = t >> 6;
  int m = lane & 15, quad = lane >> 4;

  // stage slab 0
  #pragma unroll
  for (int i=0;i<PREN;i++){
    int e = t*8 + i*BS*8;
    if (e < COUT*KW){
      int n = e / KW, c = e - n*KW;
      *(uint4*)(&B[0][n*BP + c]) = *(const uint4*)(wg + e);
    }
  }

  int row = row0 + wave*16 + m;
  bool rv = row < nrows;
  int z=0, y=0, x=0;
  {
    int s = list[rv ? row : row0];
    z = s/(HO*WO); int rem = s - z*(HO*WO); y = rem/WO; x = rem - y*WO;
  }
  __syncthreads();

  f32x4 acc[NT];
  #pragma unroll
  for (int i=0;i<NT;i++) acc[i] = (f32x4){0.f,0.f,0.f,0.f};

  #pragma unroll
  for (int g=0; g<9; g++){
    // prefetch next B slab into registers (overlaps with compute below)
    uint4 pre[PREN];
    if (g < 8){
      const unsigned short* src = wg + (size_t)(g+1)*COUT*KW;
      #pragma unroll
      for (int i=0;i<PREN;i++){
        int e = t*8 + i*BS*8;
        pre[i] = (e < COUT*KW) ? *(const uint4*)(src + e) : (uint4){0,0,0,0};
      }
    }
    int dz = g/3, dy = g - dz*3;
    int zz = STR*z - PZ + dz, yy = STR*y - PY + dy, xx0 = STR*x - PX;
    bool zyok = rv && (unsigned)zz < (unsigned)DI && (unsigned)yy < (unsigned)HI;
    int base = ((zz*HI + yy)*WI + xx0)*CIN;
    // A fragments: direct 16B loads, x-run contiguous
    bf16x8 av[KT];
    #pragma unroll
    for (int kt=0; kt<KT; kt++){
      constexpr int dummy = 0; (void)dummy;
      int tapx = (kt*32)/CIN;              // compile-time per kt (quad*8 < CIN granularity)
      int kk = kt*32 + quad*8;
      av[kt] = (bf16x8){0,0,0,0,0,0,0,0};
      if (zyok && (unsigned)(xx0 + tapx) < (unsigned)WI)
        av[kt] = *(const bf16x8*)(gin + (size_t)(base + kk));
    }
    #pragma unroll
    for (int kt=0; kt<KT; kt++){
      #pragma unroll
      for (int nt=0; nt<NT; nt++){
        bf16x8 b = *(const bf16x8*)(&B[g&1][(nt*16 + m)*BP + kt*32 + quad*8]);
        acc[nt] = __builtin_amdgcn_mfma_f32_16x16x32_bf16(av[kt], b, acc[nt], 0, 0, 0);
      }
    }
    if (g < 8){
      #pragma unroll
      for (int i=0;i<PREN;i++){
        int e = t*8 + i*BS*8;
        if (e < COUT*KW){
          int n = e / KW, c = e - n*KW;
          *(uint4*)(&B[(g+1)&1][n*BP + c]) = pre[i];
        }
      }
    }
    __syncthreads();
  }

  #pragma unroll
  for (int nt=0; nt<NT; nt++){
    int cout = nt*16 + m;
    float bv = bias[cout];
    #pragma unroll
    for (int rg=0; rg<4; rg++){
      int rw = row0 + wave*16 + quad*4 + rg;
      if (rw < nrows){
        int s = list[rw];
        gout[(size_t)s*COUT + cout] = f2bf(fmaxf(acc[nt][rg] + bv, 0.f));
      }
    }
  }
}

// ---- final: spconv 64->128, k=(3,1,1), stride=(2,1,1), pad 0; write [1,256,25,22] f32 ----
__global__ void conv_out_kernel(const unsigned short* __restrict__ g4,
                                const float* __restrict__ m4,
                                const float* __restrict__ wt, const float* __restrict__ bias,
                                float* __restrict__ out){
  int t = blockIdx.x*BS + threadIdx.x;
  if (t >= 128*DOo*HOo*WOo) return;
  int cout = t & 127; int s = t >> 7;
  int d = s/(HOo*WOo); int r = s - d*(HOo*WOo); int h = r/WOo; int w = r - h*WOo;
  float res = 0.f;
  bool act = false;
  float acc = bias[cout];
  for (int dz=0; dz<3; dz++){
    int z4 = 2*d + dz;
    int site = (z4*H4 + h)*W4 + w;
    if (m4[site] == 0.f) continue;
    act = true;
    const uint4* fr = (const uint4*)(g4 + (size_t)site*64);
    const float* wk = wt + dz*64*128 + cout;
    #pragma unroll
    for (int q=0; q<8; q++) acc8(acc, fr[q], wk + q*8*128, 128);
  }
  if (act) res = fmaxf(acc, 0.f);
  out[((cout*DOo + d)*HOo + h)*WOo + w] = res;
}

extern "C" void kernel_launch(void* const* d_in, const int* in_sizes, int n_in,
                              void* d_out, int out_size, void* d_ws, size_t ws_size,
                              hipStream_t stream){
  const float* x    = (const float*)d_in[0];
  const float* mask = (const float*)d_in[1];
  const float* w[12]; const float* bnp[12];
  for (int i=0;i<12;i++){ w[i]=(const float*)d_in[2+2*i]; bnp[i]=(const float*)d_in[3+2*i]; }

  char* base = (char*)d_ws; size_t off = 0;
  auto alloc = [&](size_t b)->void*{ void* p = base + off; off = (off + b + 255) & ~(size_t)255; return p; };

  // --- region zeroed every call (one memset) ---
  int* cnt   = (int*)alloc(16);                         // [c1,c2,c3,c4]
  int* I1    = (int*)alloc((size_t)N1v*4);              // site -> row+1 (0 = inactive)
  unsigned short* g2a = (unsigned short*)alloc((size_t)N2v*32*2);
  unsigned short* g2b = (unsigned short*)alloc((size_t)N2v*32*2);
  unsigned short* g3a = (unsigned short*)alloc((size_t)N3v*64*2);
  unsigned short* g3b = (unsigned short*)alloc((size_t)N3v*64*2);
  unsigned short* g4a = (unsigned short*)alloc((size_t)N4v*64*2);
  unsigned short* g4b = (unsigned short*)alloc((size_t)N4v*64*2);
  size_t zero_bytes = off;
  // --- fully-overwritten-before-read buffers ---
  int* list1 = (int*)alloc((size_t)ROWS1*4);
  unsigned short* f1a = (unsigned short*)alloc((size_t)ROWS1*16*2);
  unsigned short* f1b = (unsigned short*)alloc((size_t)ROWS1*16*2);
  float* m2 = (float*)alloc((size_t)N2v*4);
  int* list2 = (int*)alloc((size_t)N2v*4);
  float* m3 = (float*)alloc((size_t)N3v*4);
  int* list3 = (int*)alloc((size_t)N3v*4);
  float* m4 = (float*)alloc((size_t)N4v*4);
  int* list4 = (int*)alloc((size_t)N4v*4);

  static const int Oa[12]={16,16,32,32,32,64,64,64,64,64,64,128};
  static const int Ia[12]={ 4,16,16,32,32,32,64,64,64,64,64, 64};
  static const int Ka[12]={27,27,27,27,27,27,27,27,27,27,27,  3};
  static const int Ma[12]={ 0, 2, 2, 3, 3, 3, 3, 3, 3, 3, 3,  0};  // prep mode
  float* wt[12]; float* bs[12]; unsigned short* wbt[12];
  for (int i=0;i<12;i++){
    bs[i] = (float*)alloc((size_t)Oa[i]*4);
    wt[i]=nullptr; wbt[i]=nullptr;
    if (Ma[i]==0)      wt[i]  = (float*)alloc((size_t)Oa[i]*Ia[i]*Ka[i]*4);
    else if (Ma[i]==3) wbt[i] = (unsigned short*)alloc((size_t)Oa[i]*Ia[i]*27*2);
    else               wbt[i] = (unsigned short*)alloc((size_t)14*Oa[i]*32*2);
  }

  hipMemsetAsync(base, 0, zero_bytes, stream);

  // fused weight prep
  PrepArgs pa;
  pa.off[0] = 0;
  for (int i=0;i<12;i++){
    pa.w[i]=w[i]; pa.bn[i]=bnp[i]; pa.bias[i]=bs[i];
    pa.O[i]=Oa[i]; pa.I[i]=Ia[i]; pa.K[i]=Ka[i]; pa.mode[i]=Ma[i];
    pa.dst[i] = (Ma[i]==0) ? (void*)wt[i] : (void*)wbt[i];
    int tot = (Ma[i]==2) ? 14*Oa[i]*32 : Oa[i]*Ia[i]*Ka[i];
    pa.off[i+1] = pa.off[i] + tot;
  }
  prep_all<<<(pa.off[12]+BS-1)/BS, BS, 0, stream>>>(pa);

  // level-1 compaction
  build_list1_kernel<<<(N1v + BS*16 - 1)/(BS*16), BS, 0, stream>>>(mask, I1, list1, cnt);

  // level 1: subm 4->16 scalar, then subm 16->16 MFMA
  subm_l0_kernel<<<(ROWS1*16)/BS, BS, 0, stream>>>(x, list1, cnt, wt[0], bs[0], f1a);
  conv_mfma_l1_kernel<16,H1,W1,1,1,1,1,false><<<ROWS1/64, 256, 0, stream>>>
      (f1a, I1, list1, cnt, 0, wbt[1], bs[1], f1b);

  // level 1 -> 2: mask + MFMA spconv 16->32 into zeroed dense grid
  build_mask_kernel<D1,H1,W1,D2,H2,W2,1,1,1><<<(N2v + BS*4 - 1)/(BS*4), BS, 0, stream>>>(mask, m2, list2, cnt+1);
  conv_mfma_l1_kernel<32,H2,W2,1,1,1,2,true><<<(N2v+63)/64, 256, 0, stream>>>
      (f1b, I1, list2, cnt, 1, wbt[2], bs[2], g2a);

  // level-2 subm convs (MFMA direct), 32ch
  {
    int nb = (N2v + 63)/64;
    conv_mfma2_kernel<32,32,D2,H2,W2,H2,W2,1,1,1,1><<<nb, 256, 0, stream>>>(g2a, list2, cnt, 1, wbt[3], bs[3], g2b);
    conv_mfma2_kernel<32,32,D2,H2,W2,H2,W2,1,1,1,1><<<nb, 256, 0, stream>>>(g2b, list2, cnt, 1, wbt[4], bs[4], g2a);
  }

  // level 2 -> 3 (spconv 32->64) + level-3 subm convs
  build_mask_kernel<D2,H2,W2,D3,H3,W3,1,1,1><<<(N3v + BS*4 - 1)/(BS*4), BS, 0, stream>>>(m2, m3, list3, cnt+2);
  {
    int nb = (N3v + 63)/64;
    conv_mfma2_kernel<32,64,D2,H2,W2,H3,W3,1,1,1,2><<<nb, 256, 0, stream>>>(g2a, list3, cnt, 2, wbt[5], bs[5], g3a);
    conv_mfma2_kernel<64,64,D3,H3,W3,H3,W3,1,1,1,1><<<nb, 256, 0, stream>>>(g3a, list3, cnt, 2, wbt[6], bs[6], g3b);
    conv_mfma2_kernel<64,64,D3,H3,W3,H3,W3,1,1,1,1><<<nb, 256, 0, stream>>>(g3b, list3, cnt, 2, wbt[7], bs[7], g3a);
  }

  // level 3 -> 4 (spconv pad (0,1,1)) + level-4 subm convs
  build_mask_kernel<D3,H3,W3,D4,H4,W4,0,1,1><<<(N4v + BS*4 - 1)/(BS*4), BS, 0, stream>>>(m3, m4, list4, cnt+3);
  {
    int nb = (N4v + 63)/64;
    conv_mfma2_kernel<64,64,D3,H3,W3,H4,W4,0,1,1,2><<<nb, 256, 0, stream>>>(g3a, list4, cnt, 3, wbt[8], bs[8], g4a);
    conv_mfma2_kernel<64,64,D4,H4,W4,H4,W4,1,1,1,1><<<nb, 256, 0, stream>>>(g4a, list4, cnt, 3, wbt[9], bs[9], g4b);
    conv_mfma2_kernel<64,64,D4,H4,W4,H4,W4,1,1,1,1><<<nb, 256, 0, stream>>>(g4b, list4, cnt, 3, wbt[10], bs[10], g4a);
  }

  // final spconv (3,1,1)/(2,1,1)/pad0 -> [1,256,25,22]
  conv_out_kernel<<<(128*DOo*HOo*WOo)/BS, BS, 0, stream>>>(g4a, m4, wt[11], bs[11], (float*)d_out);
}